// Round 21
// baseline (219.626 us; speedup 1.0000x reference)
//
#include <hip/hip_runtime.h>

typedef float  f32x4  __attribute__((ext_vector_type(4)));
typedef float  f4v    __attribute__((ext_vector_type(4)));
typedef __bf16 bf16x8 __attribute__((ext_vector_type(8)));
typedef __bf16 bf16x4 __attribute__((ext_vector_type(4)));
typedef unsigned short ushort_t;

#define AS1 __attribute__((address_space(1)))
#define AS3 __attribute__((address_space(3)))

static __device__ __forceinline__ void gload_lds16(const void* g, void* l) {
  __builtin_amdgcn_global_load_lds((const AS1 void*)g, (AS3 void*)l, 16, 0, 0);
}

// mish(x) = x * u/(u+2), u = t*(t+2), t = e^x; guard large x.
static __device__ __forceinline__ float mishf(float x) {
  float t = __expf(x);
  float u = t * (t + 2.f);
  float y = x * __fdividef(u, u + 2.f);
  return (x > 15.f) ? x : y;
}

// ---------------- weight pack: fp32 -> bf16 in MFMA-fragment order --------
// idx = ((((cb*KC + c)*8 + u)*2 + n)*64 + l)*8 holds
// W[cb*32 + n*16 + (l&15)][c*256 + u*32 + (l>>4)*8 .. +8].
// Block 384 additionally packs the qkv bias (768 floats).
__global__ __launch_bounds__(256) void packw(
    const float* __restrict__ Wq, const float* __restrict__ Wk,
    const float* __restrict__ Wv, const float* __restrict__ Wp,
    const float* __restrict__ W1, const float* __restrict__ W2,
    const float* __restrict__ bq, const float* __restrict__ bk,
    const float* __restrict__ bv, __bf16* __restrict__ out,
    float* __restrict__ bqkv)
{
  if (blockIdx.x == 384) {
    #pragma unroll
    for (int j = 0; j < 3; ++j) {
      const int i = j * 256 + threadIdx.x;
      bqkv[i] = (i < 256) ? bq[i] : (i < 512 ? bk[i - 256] : bv[i - 512]);
    }
    return;
  }
  const int t = blockIdx.x * 256 + threadIdx.x;   // 98304 threads
  const int e0 = t * 8;
  int rel, K; const float* src;
  if      (e0 < 196608) { rel = e0;          K = 256;  src = nullptr; }
  else if (e0 < 262144) { rel = e0 - 196608; K = 256;  src = Wp; }
  else if (e0 < 524288) { rel = e0 - 262144; K = 256;  src = W1; }
  else                  { rel = e0 - 524288; K = 1024; src = W2; }
  const int percb = (K >> 8) * 8192;
  const int cb = rel / percb;  const int r1 = rel % percb;
  const int c  = r1 / 8192;    const int r2 = r1 % 8192;
  const int u  = r2 / 1024;    const int r3 = r2 % 1024;
  const int n  = r3 / 512;     const int l  = (r3 % 512) >> 3;
  const int col = cb * 32 + n * 16 + (l & 15);
  const int k   = c * 256 + u * 32 + ((l >> 4) << 3);
  const float* sp;
  if (e0 < 196608) {
    const float* qkvsrc = (col < 256) ? Wq : (col < 512 ? Wk : Wv);
    sp = qkvsrc + (size_t)(col & 255) * 256 + k;
  } else {
    sp = src + (size_t)col * K + k;
  }
  const f4v a = *(const f4v*)(sp);
  const f4v b = *(const f4v*)(sp + 4);
  bf16x8 o;
  #pragma unroll
  for (int j = 0; j < 4; ++j) { o[j] = (__bf16)a[j]; o[4 + j] = (__bf16)b[j]; }
  *(bf16x8*)(out + e0) = o;
}

// ---------------- B-streamed GEMM with optional LN fusion -----------------
template<int BM, int NT, int KC, int ACT, int RES, int OUTBF,
         int LNSTAGE, int LNFUSE, int RESBF>
__global__ __launch_bounds__(512, 2) void bgemm(
    const __bf16* __restrict__ A, const float* __restrict__ Xf,
    const __bf16* __restrict__ Wg, const float* __restrict__ bias,
    const void* __restrict__ res, const float* __restrict__ lnw,
    const float* __restrict__ lnb, void* __restrict__ out,
    void* __restrict__ out2, int ldo)
{
  constexpr int K  = KC * 256;
  constexpr int MR = BM / 32;              // m-frags per wave (BM/2 rows)
  __shared__ __bf16 Ab[BM * 256];
  __shared__ float redS[64][4];
  __shared__ float redQ[64][4];
  const int tid = threadIdx.x, l = tid & 63, w = tid >> 6;
  const int wr = w >> 2, wc = w & 3;
  constexpr int nwg = (32768 / BM) * NT;
  const int wg = (blockIdx.x & 7) * (nwg / 8) + (blockIdx.x >> 3);
  const int mt = wg / NT, nt = wg % NT;
  const int row0 = mt * BM;
  const int col0 = nt * 256 + wc * 64;
  const int cb0 = nt * 8 + wc * 2;         // first of two 32-col blocks

  auto stageA = [&](int c) {
    #pragma unroll
    for (int j = 0; j < BM / 16; ++j) {
      const int s = j * 512 + tid;         // 16B unit index
      const int r = s >> 5, q = s & 31;
      gload_lds16(A + (size_t)(row0 + r) * K + c * 256 + ((q ^ (r & 7)) << 3),
                  &Ab[s << 3]);
    }
  };

  auto ldBu = [&](bf16x8* d, int c, int u) {
    const __bf16* wp0 = Wg + ((size_t)cb0 * KC + c) * 8192 + (((u << 1) * 64 + l) << 3);
    const __bf16* wp1 = wp0 + (size_t)KC * 8192;
    d[0] = *(const bf16x8*)(wp0);
    d[1] = *(const bf16x8*)(wp0 + 512);
    d[2] = *(const bf16x8*)(wp1);
    d[3] = *(const bf16x8*)(wp1 + 512);
  };

  f32x4 acc[MR][4] = {};

  if constexpr (LNSTAGE) {
    const int q = tid & 31;
    const f4v ga0 = *(const f4v*)(lnw + q * 8);
    const f4v ga1 = *(const f4v*)(lnw + q * 8 + 4);
    const f4v bb0 = *(const f4v*)(lnb + q * 8);
    const f4v bb1 = *(const f4v*)(lnb + q * 8 + 4);
    #pragma unroll
    for (int j = 0; j < BM / 16; ++j) {
      const int s = j * 512 + tid, r = s >> 5;
      const float* xp = Xf + (size_t)(row0 + r) * 256 + q * 8;
      const f4v xa = *(const f4v*)xp;
      const f4v xb = *(const f4v*)(xp + 4);
      float s1 = xa[0] + xa[1] + xa[2] + xa[3] + xb[0] + xb[1] + xb[2] + xb[3];
      float s2 = xa[0]*xa[0] + xa[1]*xa[1] + xa[2]*xa[2] + xa[3]*xa[3]
               + xb[0]*xb[0] + xb[1]*xb[1] + xb[2]*xb[2] + xb[3]*xb[3];
      #pragma unroll
      for (int mk = 1; mk < 32; mk <<= 1) {
        s1 += __shfl_xor(s1, mk); s2 += __shfl_xor(s2, mk);
      }
      const float mu = s1 * (1.f / 256.f);
      const float rs = rsqrtf(s2 * (1.f / 256.f) - mu * mu + 1e-5f);
      bf16x8 o;
      #pragma unroll
      for (int i = 0; i < 4; ++i) {
        o[i]     = (__bf16)((xa[i] - mu) * rs * ga0[i] + bb0[i]);
        o[4 + i] = (__bf16)((xb[i] - mu) * rs * ga1[i] + bb1[i]);
      }
      *(bf16x8*)&Ab[((r << 5) | (q ^ (r & 7))) << 3] = o;
    }
    __syncthreads();
  } else {
    stageA(0);
    asm volatile("s_waitcnt vmcnt(0)" ::: "memory");
    __builtin_amdgcn_s_barrier();
  }

  for (int c = 0;;) {
    bf16x8 b0[4], b1[4];
    ldBu(b0, c, 0);
    #pragma unroll
    for (int u = 0; u < 8; ++u) {
      if (u + 1 < 8) ldBu((u & 1) ? b0 : b1, c, u + 1);
      const bf16x8* bu = (u & 1) ? b1 : b0;
      bf16x8 af[MR];
      #pragma unroll
      for (int m = 0; m < MR; ++m) {
        const int r = wr * (BM / 2) + m * 16 + (l & 15);
        const int q = ((u << 2) | (l >> 4)) ^ (r & 7);
        af[m] = *(const bf16x8*)&Ab[((r << 5) | q) << 3];
      }
      #pragma unroll
      for (int m = 0; m < MR; ++m)
        #pragma unroll
        for (int n = 0; n < 4; ++n)
          acc[m][n] = __builtin_amdgcn_mfma_f32_16x16x32_bf16(af[m], bu[n], acc[m][n], 0, 0, 0);
    }
    if (++c == KC) break;
    __syncthreads();
    stageA(c);
    asm volatile("s_waitcnt vmcnt(0)" ::: "memory");
    __builtin_amdgcn_s_barrier();
  }

  float bs[4];
  #pragma unroll
  for (int n = 0; n < 4; ++n) bs[n] = bias[col0 + n * 16 + (l & 15)];

  if constexpr (LNFUSE) {
    #pragma unroll
    for (int m = 0; m < MR; ++m) {
      #pragma unroll
      for (int r = 0; r < 4; ++r) {
        const int row = row0 + wr * (BM / 2) + m * 16 + ((l >> 4) << 2) + r;
        const float* rp = (const float*)res + (size_t)row * ldo + col0;
        float s1v = 0.f, s2v = 0.f;
        #pragma unroll
        for (int n = 0; n < 4; ++n) {
          float v = acc[m][n][r] + bs[n] + rp[n * 16 + (l & 15)];
          acc[m][n][r] = v;
          s1v += v; s2v += v * v;
        }
        #pragma unroll
        for (int mk = 1; mk < 16; mk <<= 1) {
          s1v += __shfl_xor(s1v, mk); s2v += __shfl_xor(s2v, mk);
        }
        if ((l & 15) == 0) { redS[row - row0][wc] = s1v; redQ[row - row0][wc] = s2v; }
      }
    }
    __syncthreads();
    float wlv[4], blv[4];
    #pragma unroll
    for (int n = 0; n < 4; ++n) {
      wlv[n] = lnw[col0 + n * 16 + (l & 15)];
      blv[n] = lnb[col0 + n * 16 + (l & 15)];
    }
    #pragma unroll
    for (int m = 0; m < MR; ++m) {
      #pragma unroll
      for (int r = 0; r < 4; ++r) {
        const int row = row0 + wr * (BM / 2) + m * 16 + ((l >> 4) << 2) + r;
        const int lrow = row - row0;
        const f4v ss = *(const f4v*)redS[lrow];
        const f4v qq = *(const f4v*)redQ[lrow];
        const float mu = (ss[0] + ss[1] + ss[2] + ss[3]) * (1.f / 256.f);
        const float var = (qq[0] + qq[1] + qq[2] + qq[3]) * (1.f / 256.f) - mu * mu;
        const float rsv = rsqrtf(var + 1e-5f);
        __bf16* o1 = (__bf16*)out  + (size_t)row * ldo + col0;
        __bf16* o2 = (__bf16*)out2 + (size_t)row * ldo + col0;
        #pragma unroll
        for (int n = 0; n < 4; ++n) {
          const float v = acc[m][n][r];
          o1[n * 16 + (l & 15)] = (__bf16)v;
          o2[n * 16 + (l & 15)] = (__bf16)((v - mu) * rsv * wlv[n] + blv[n]);
        }
      }
    }
  } else {
    #pragma unroll
    for (int m = 0; m < MR; ++m) {
      #pragma unroll
      for (int r = 0; r < 4; ++r) {
        const int row = row0 + wr * (BM / 2) + m * 16 + ((l >> 4) << 2) + r;
        float v[4];
        #pragma unroll
        for (int n = 0; n < 4; ++n) {
          v[n] = acc[m][n][r] + bs[n];
          if (ACT) v[n] = mishf(v[n]);
        }
        if (RES) {
          if constexpr (RESBF) {
            const __bf16* rp = (const __bf16*)res + (size_t)row * ldo + col0;
            #pragma unroll
            for (int n = 0; n < 4; ++n) v[n] += (float)rp[n * 16 + (l & 15)];
          } else {
            const float* rp = (const float*)res + (size_t)row * ldo + col0;
            #pragma unroll
            for (int n = 0; n < 4; ++n) v[n] += rp[n * 16 + (l & 15)];
          }
        }
        if (OUTBF) {
          __bf16* op = (__bf16*)out + (size_t)row * ldo + col0;
          #pragma unroll
          for (int n = 0; n < 4; ++n) op[n * 16 + (l & 15)] = (__bf16)v[n];
        } else {
          float* op = (float*)out + (size_t)row * ldo + col0;
          #pragma unroll
          for (int n = 0; n < 4; ++n) op[n * 16 + (l & 15)] = v[n];
        }
      }
    }
  }
}

// ---------------- flash attention, e-split PV (register diet) -------------
// R9 structure, but each 16-q-row group is served by TWO waves: both
// compute QK^T (duplicated, cheap), each does PV for 128 of 256 e-cols.
// acc[8] = 32 AGPR -> total regs <= 128 -> 16 waves/CU (2 blocks co-
// resident), doubling latency-hiding on the QK->exp->Ps->PV chain.
// Block 512 thr / 8 waves = 4 q-groups x 2 e-halves = 64 q-rows; grid 512.
__global__ __launch_bounds__(512, 4) void attn_fwd(
    const __bf16* __restrict__ QKV, __bf16* __restrict__ Om)
{
  __shared__ __bf16 Ks[2][32][256];   // K tile, XOR-swizzled rows
  __shared__ __bf16 Vs[2][256][32];   // V^T tile [n][k]
  __shared__ __bf16 Ps[8][16][32];    // per-wave P relayout buffer
  const int tid = threadIdx.x, l = tid & 63, w = tid >> 6;
  const int wgs = (blockIdx.x & 7) * 64 + (blockIdx.x >> 3);
  const int bh = wgs >> 4, qt = wgs & 15;
  const size_t rbase = (size_t)bh * 1024 * 768;   // bh row base in QKV
  const int qr0 = qt * 64 + (w >> 1) * 16;
  const int eh = w & 1;                // e-half for PV

  bf16x8 qf[8];
  {
    const __bf16* qp = QKV + rbase + (size_t)(qr0 + (l & 15)) * 768 + ((l >> 4) << 3);
    #pragma unroll
    for (int s = 0; s < 8; ++s) qf[s] = *(const bf16x8*)(qp + s * 32);
  }
  f32x4 acc[8] = {};
  float lacc[4] = {0.f, 0.f, 0.f, 0.f};

  const int kec = tid & 31, kr_ = tid >> 5;
  const int vp = tid & 15, vc = tid >> 4;
  const __bf16* gK = QKV + 256 + rbase + kec * 8;
  const __bf16* gV = QKV + 512 + rbase + vc * 8;

  uint4 rk0, rk1, rv0, rv1;
  auto ldKV = [&](int kt) {
    const __bf16* k0 = gK + (size_t)(kt * 32 + kr_) * 768;
    rk0 = *(const uint4*)k0;
    rk1 = *(const uint4*)(k0 + 16 * 768);
    const __bf16* v0 = gV + (size_t)(kt * 32 + vp * 2) * 768;
    rv0 = *(const uint4*)v0;
    rv1 = *(const uint4*)(v0 + 768);
  };
  auto wrKV = [&](int buf) {
    char* kb = (char*)&Ks[buf][0][0];
    const int a0 = (kr_ * 512 + kec * 16) ^ ((kr_ & 15) << 4);
    const int a1 = ((kr_ + 16) * 512 + kec * 16) ^ (((kr_ + 16) & 15) << 4);
    *(uint4*)(kb + a0) = rk0;
    *(uint4*)(kb + a1) = rk1;
    const ushort_t* s0 = (const ushort_t*)&rv0;
    const ushort_t* s1 = (const ushort_t*)&rv1;
    #pragma unroll
    for (int i = 0; i < 8; ++i) {
      unsigned pk = (unsigned)s0[i] | ((unsigned)s1[i] << 16);
      *(unsigned*)&Vs[buf][vc * 8 + i][vp * 2] = pk;
    }
  };

  ldKV(0); wrKV(0);
  __syncthreads();
  int cur = 0;
  for (int kt = 0;;) {
    if (kt + 1 < 32) ldKV(kt + 1);
    f32x4 S[2] = {};
    const char* kbase = (const char*)&Ks[cur][0][0];
    #pragma unroll
    for (int t = 0; t < 2; ++t) {
      const int kcol = t * 16 + (l & 15);
      const int swz = (kcol & 15) << 4;
      #pragma unroll
      for (int s = 0; s < 8; ++s) {
        uint4 kf = *(const uint4*)(kbase + ((kcol * 512 + s * 64 + ((l >> 4) << 4)) ^ swz));
        S[t] = __builtin_amdgcn_mfma_f32_16x16x32_bf16(qf[s], __builtin_bit_cast(bf16x8, kf), S[t], 0, 0, 0);
      }
    }
    #pragma unroll
    for (int t = 0; t < 2; ++t)
      #pragma unroll
      for (int r = 0; r < 4; ++r) {
        float p = __expf(S[t][r]);
        lacc[r] += p;
        Ps[w][((l >> 4) << 2) + r][t * 16 + (l & 15)] = (__bf16)p;
      }
    bf16x8 pf = *(const bf16x8*)&Ps[w][l & 15][(l >> 4) << 3];
    #pragma unroll
    for (int n = 0; n < 8; ++n) {
      uint4 vf = *(const uint4*)&Vs[cur][eh * 128 + n * 16 + (l & 15)][(l >> 4) << 3];
      acc[n] = __builtin_amdgcn_mfma_f32_16x16x32_bf16(pf, __builtin_bit_cast(bf16x8, vf), acc[n], 0, 0, 0);
    }
    if (++kt == 32) break;
    wrKV(cur ^ 1);
    __syncthreads();
    cur ^= 1;
  }
  f32x4 inv;
  #pragma unroll
  for (int r = 0; r < 4; ++r) {
    float s = lacc[r];
    s += __shfl_xor(s, 1); s += __shfl_xor(s, 2);
    s += __shfl_xor(s, 4); s += __shfl_xor(s, 8);
    inv[r] = 1.f / (16.f * s);
  }
  __bf16* op = Om + (size_t)(bh * 1024 + qr0 + ((l >> 4) << 2)) * 256
             + eh * 128 + (l & 15);
  #pragma unroll
  for (int n = 0; n < 8; ++n)
    #pragma unroll
    for (int r = 0; r < 4; ++r)
      op[(size_t)r * 256 + n * 16] = (__bf16)(acc[n][r] * inv[r]);
}

// ---------------- host launch ----------------
extern "C" void kernel_launch(void* const* d_in, const int* in_sizes, int n_in,
                              void* d_out, int out_size, void* d_ws, size_t ws_size,
                              hipStream_t stream)
{
  const float* x    = (const float*)d_in[0];
  const float* ln1w = (const float*)d_in[1];
  const float* ln1b = (const float*)d_in[2];
  const float* Wq   = (const float*)d_in[3];
  const float* bq   = (const float*)d_in[4];
  const float* Wk   = (const float*)d_in[5];
  const float* bk   = (const float*)d_in[6];
  const float* Wv   = (const float*)d_in[7];
  const float* bv   = (const float*)d_in[8];
  const float* Wp   = (const float*)d_in[9];
  const float* bp   = (const float*)d_in[10];
  const float* ln2w = (const float*)d_in[11];
  const float* ln2b = (const float*)d_in[12];
  const float* W1   = (const float*)d_in[13];
  const float* b1   = (const float*)d_in[14];
  const float* W2   = (const float*)d_in[15];
  const float* b2   = (const float*)d_in[16];

  // ws layout (bytes):
  char* ws = (char*)d_ws;
  __bf16* wb   = (__bf16*)(ws);               // packed bf16 weights (1.5 MB)
  float*  bqkv = (float*)(ws + 1572864);      // packed qkv bias (3 KB)
  __bf16* y    = (__bf16*)(ws + 2097152);     // attn out (16 MB)
  __bf16* qkv  = (__bf16*)(ws + 18874368);    // packed QKV [M][768] (48 MB)
  __bf16* x1b  = (__bf16*)(ws + 18874368);    // x1 residual bf16 (16 MB, aliases qkv lo)
  __bf16* hb   = (__bf16*)(ws + 52428800);    // LN2 out (16 MB, aliases qkv hi)
  __bf16* h1   = (__bf16*)(ws + 69206016);    // MLP hidden (64 MB)
  __bf16* ao   = y;
  float*  outp = (float*)d_out;

  packw<<<385, 256, 0, stream>>>(Wq, Wk, Wv, Wp, W1, W2, bq, bk, bv, wb, bqkv);
  // QKV with fused LN1: A = LN(x) staged in-register
  bgemm<128, 3, 1, 0, 0, 1, 1, 0, 0><<<768, 512, 0, stream>>>(
      nullptr, x, wb, bqkv, nullptr, ln1w, ln1b, qkv, nullptr, 768);
  attn_fwd<<<512, 512, 0, stream>>>(qkv, ao);
  // proj with fused LN2: writes x1 (bf16) + hb = LN2(x1) (bf16); res = x fp32
  bgemm<64, 1, 1, 0, 1, 0, 0, 1, 0><<<512, 512, 0, stream>>>(
      ao, nullptr, wb + 196608, bp, x, ln2w, ln2b, x1b, hb, 256);
  // MLP1: mish, bf16 out [32768][1024]
  bgemm<128, 4, 1, 1, 0, 1, 0, 0, 0><<<1024, 512, 0, stream>>>(
      hb, nullptr, wb + 262144, b1, nullptr, nullptr, nullptr, h1, nullptr, 1024);
  // MLP2: K=1024, mish + x1 residual (bf16), fp32 out
  bgemm<64, 1, 4, 1, 1, 0, 0, 0, 1><<<512, 512, 0, stream>>>(
      h1, nullptr, wb + 524288, b2, x1b, nullptr, nullptr, outp, nullptr, 256);
}

// Round 22
// 194.900 us; speedup vs baseline: 1.1269x; 1.1269x over previous
//
#include <hip/hip_runtime.h>

typedef float  f32x4  __attribute__((ext_vector_type(4)));
typedef float  f4v    __attribute__((ext_vector_type(4)));
typedef __bf16 bf16x8 __attribute__((ext_vector_type(8)));
typedef __bf16 bf16x4 __attribute__((ext_vector_type(4)));
typedef unsigned short ushort_t;

#define AS1 __attribute__((address_space(1)))
#define AS3 __attribute__((address_space(3)))

static __device__ __forceinline__ void gload_lds16(const void* g, void* l) {
  __builtin_amdgcn_global_load_lds((const AS1 void*)g, (AS3 void*)l, 16, 0, 0);
}

// mish(x) = x * u/(u+2), u = t*(t+2), t = e^x; guard large x.
static __device__ __forceinline__ float mishf(float x) {
  float t = __expf(x);
  float u = t * (t + 2.f);
  float y = x * __fdividef(u, u + 2.f);
  return (x > 15.f) ? x : y;
}

// ---------------- weight pack: fp32 -> bf16 in MFMA-fragment order --------
// idx = ((((cb*KC + c)*8 + u)*2 + n)*64 + l)*8 holds
// W[cb*32 + n*16 + (l&15)][c*256 + u*32 + (l>>4)*8 .. +8].
// Block 384 additionally packs the qkv bias (768 floats).
__global__ __launch_bounds__(256) void packw(
    const float* __restrict__ Wq, const float* __restrict__ Wk,
    const float* __restrict__ Wv, const float* __restrict__ Wp,
    const float* __restrict__ W1, const float* __restrict__ W2,
    const float* __restrict__ bq, const float* __restrict__ bk,
    const float* __restrict__ bv, __bf16* __restrict__ out,
    float* __restrict__ bqkv)
{
  if (blockIdx.x == 384) {
    #pragma unroll
    for (int j = 0; j < 3; ++j) {
      const int i = j * 256 + threadIdx.x;
      bqkv[i] = (i < 256) ? bq[i] : (i < 512 ? bk[i - 256] : bv[i - 512]);
    }
    return;
  }
  const int t = blockIdx.x * 256 + threadIdx.x;   // 98304 threads
  const int e0 = t * 8;
  int rel, K; const float* src;
  if      (e0 < 196608) { rel = e0;          K = 256;  src = nullptr; }
  else if (e0 < 262144) { rel = e0 - 196608; K = 256;  src = Wp; }
  else if (e0 < 524288) { rel = e0 - 262144; K = 256;  src = W1; }
  else                  { rel = e0 - 524288; K = 1024; src = W2; }
  const int percb = (K >> 8) * 8192;
  const int cb = rel / percb;  const int r1 = rel % percb;
  const int c  = r1 / 8192;    const int r2 = r1 % 8192;
  const int u  = r2 / 1024;    const int r3 = r2 % 1024;
  const int n  = r3 / 512;     const int l  = (r3 % 512) >> 3;
  const int col = cb * 32 + n * 16 + (l & 15);
  const int k   = c * 256 + u * 32 + ((l >> 4) << 3);
  const float* sp;
  if (e0 < 196608) {
    const float* qkvsrc = (col < 256) ? Wq : (col < 512 ? Wk : Wv);
    sp = qkvsrc + (size_t)(col & 255) * 256 + k;
  } else {
    sp = src + (size_t)col * K + k;
  }
  const f4v a = *(const f4v*)(sp);
  const f4v b = *(const f4v*)(sp + 4);
  bf16x8 o;
  #pragma unroll
  for (int j = 0; j < 4; ++j) { o[j] = (__bf16)a[j]; o[4 + j] = (__bf16)b[j]; }
  *(bf16x8*)(out + e0) = o;
}

// ---------------- B-streamed GEMM with optional LN fusion -----------------
// out[M=32768][ldo](+nt*256) = act(A @ W^T + bias) (+res). K = KC*256.
// Block 512 thr / 8 waves (2x4): wave owns BM/2 rows x 64 cols.
// LNSTAGE: A = LayerNorm(Xf) computed during staging.
// LNFUSE (BM=64, NT=1): epilogue computes x1 = acc+bias+x, block LN,
//   writes x1 (bf16) AND LN2(x1) (bf16).
// RESBF: residual read as bf16.
template<int BM, int NT, int KC, int ACT, int RES, int OUTBF,
         int LNSTAGE, int LNFUSE, int RESBF>
__global__ __launch_bounds__(512, 2) void bgemm(
    const __bf16* __restrict__ A, const float* __restrict__ Xf,
    const __bf16* __restrict__ Wg, const float* __restrict__ bias,
    const void* __restrict__ res, const float* __restrict__ lnw,
    const float* __restrict__ lnb, void* __restrict__ out,
    void* __restrict__ out2, int ldo)
{
  constexpr int K  = KC * 256;
  constexpr int MR = BM / 32;              // m-frags per wave (BM/2 rows)
  __shared__ __bf16 Ab[BM * 256];
  __shared__ float redS[64][4];
  __shared__ float redQ[64][4];
  const int tid = threadIdx.x, l = tid & 63, w = tid >> 6;
  const int wr = w >> 2, wc = w & 3;
  constexpr int nwg = (32768 / BM) * NT;
  const int wg = (blockIdx.x & 7) * (nwg / 8) + (blockIdx.x >> 3);
  const int mt = wg / NT, nt = wg % NT;
  const int row0 = mt * BM;
  const int col0 = nt * 256 + wc * 64;
  const int cb0 = nt * 8 + wc * 2;         // first of two 32-col blocks

  auto stageA = [&](int c) {
    #pragma unroll
    for (int j = 0; j < BM / 16; ++j) {
      const int s = j * 512 + tid;         // 16B unit index
      const int r = s >> 5, q = s & 31;
      gload_lds16(A + (size_t)(row0 + r) * K + c * 256 + ((q ^ (r & 7)) << 3),
                  &Ab[s << 3]);
    }
  };

  auto ldBu = [&](bf16x8* d, int c, int u) {
    const __bf16* wp0 = Wg + ((size_t)cb0 * KC + c) * 8192 + (((u << 1) * 64 + l) << 3);
    const __bf16* wp1 = wp0 + (size_t)KC * 8192;
    d[0] = *(const bf16x8*)(wp0);
    d[1] = *(const bf16x8*)(wp0 + 512);
    d[2] = *(const bf16x8*)(wp1);
    d[3] = *(const bf16x8*)(wp1 + 512);
  };

  f32x4 acc[MR][4] = {};

  if constexpr (LNSTAGE) {
    const int q = tid & 31;
    const f4v ga0 = *(const f4v*)(lnw + q * 8);
    const f4v ga1 = *(const f4v*)(lnw + q * 8 + 4);
    const f4v bb0 = *(const f4v*)(lnb + q * 8);
    const f4v bb1 = *(const f4v*)(lnb + q * 8 + 4);
    #pragma unroll
    for (int j = 0; j < BM / 16; ++j) {
      const int s = j * 512 + tid, r = s >> 5;
      const float* xp = Xf + (size_t)(row0 + r) * 256 + q * 8;
      const f4v xa = *(const f4v*)xp;
      const f4v xb = *(const f4v*)(xp + 4);
      float s1 = xa[0] + xa[1] + xa[2] + xa[3] + xb[0] + xb[1] + xb[2] + xb[3];
      float s2 = xa[0]*xa[0] + xa[1]*xa[1] + xa[2]*xa[2] + xa[3]*xa[3]
               + xb[0]*xb[0] + xb[1]*xb[1] + xb[2]*xb[2] + xb[3]*xb[3];
      #pragma unroll
      for (int mk = 1; mk < 32; mk <<= 1) {
        s1 += __shfl_xor(s1, mk); s2 += __shfl_xor(s2, mk);
      }
      const float mu = s1 * (1.f / 256.f);
      const float rs = rsqrtf(s2 * (1.f / 256.f) - mu * mu + 1e-5f);
      bf16x8 o;
      #pragma unroll
      for (int i = 0; i < 4; ++i) {
        o[i]     = (__bf16)((xa[i] - mu) * rs * ga0[i] + bb0[i]);
        o[4 + i] = (__bf16)((xb[i] - mu) * rs * ga1[i] + bb1[i]);
      }
      *(bf16x8*)&Ab[((r << 5) | (q ^ (r & 7))) << 3] = o;
    }
    __syncthreads();
  } else {
    stageA(0);
    asm volatile("s_waitcnt vmcnt(0)" ::: "memory");
    __builtin_amdgcn_s_barrier();
  }

  for (int c = 0;;) {
    bf16x8 b0[4], b1[4];
    ldBu(b0, c, 0);
    #pragma unroll
    for (int u = 0; u < 8; ++u) {
      if (u + 1 < 8) ldBu((u & 1) ? b0 : b1, c, u + 1);
      const bf16x8* bu = (u & 1) ? b1 : b0;
      bf16x8 af[MR];
      #pragma unroll
      for (int m = 0; m < MR; ++m) {
        const int r = wr * (BM / 2) + m * 16 + (l & 15);
        const int q = ((u << 2) | (l >> 4)) ^ (r & 7);
        af[m] = *(const bf16x8*)&Ab[((r << 5) | q) << 3];
      }
      #pragma unroll
      for (int m = 0; m < MR; ++m)
        #pragma unroll
        for (int n = 0; n < 4; ++n)
          acc[m][n] = __builtin_amdgcn_mfma_f32_16x16x32_bf16(af[m], bu[n], acc[m][n], 0, 0, 0);
    }
    if (++c == KC) break;
    __syncthreads();
    stageA(c);
    asm volatile("s_waitcnt vmcnt(0)" ::: "memory");
    __builtin_amdgcn_s_barrier();
  }

  float bs[4];
  #pragma unroll
  for (int n = 0; n < 4; ++n) bs[n] = bias[col0 + n * 16 + (l & 15)];

  if constexpr (LNFUSE) {
    #pragma unroll
    for (int m = 0; m < MR; ++m) {
      #pragma unroll
      for (int r = 0; r < 4; ++r) {
        const int row = row0 + wr * (BM / 2) + m * 16 + ((l >> 4) << 2) + r;
        const float* rp = (const float*)res + (size_t)row * ldo + col0;
        float s1v = 0.f, s2v = 0.f;
        #pragma unroll
        for (int n = 0; n < 4; ++n) {
          float v = acc[m][n][r] + bs[n] + rp[n * 16 + (l & 15)];
          acc[m][n][r] = v;
          s1v += v; s2v += v * v;
        }
        #pragma unroll
        for (int mk = 1; mk < 16; mk <<= 1) {
          s1v += __shfl_xor(s1v, mk); s2v += __shfl_xor(s2v, mk);
        }
        if ((l & 15) == 0) { redS[row - row0][wc] = s1v; redQ[row - row0][wc] = s2v; }
      }
    }
    __syncthreads();
    float wlv[4], blv[4];
    #pragma unroll
    for (int n = 0; n < 4; ++n) {
      wlv[n] = lnw[col0 + n * 16 + (l & 15)];
      blv[n] = lnb[col0 + n * 16 + (l & 15)];
    }
    #pragma unroll
    for (int m = 0; m < MR; ++m) {
      #pragma unroll
      for (int r = 0; r < 4; ++r) {
        const int row = row0 + wr * (BM / 2) + m * 16 + ((l >> 4) << 2) + r;
        const int lrow = row - row0;
        const f4v ss = *(const f4v*)redS[lrow];
        const f4v qq = *(const f4v*)redQ[lrow];
        const float mu = (ss[0] + ss[1] + ss[2] + ss[3]) * (1.f / 256.f);
        const float var = (qq[0] + qq[1] + qq[2] + qq[3]) * (1.f / 256.f) - mu * mu;
        const float rsv = rsqrtf(var + 1e-5f);
        __bf16* o1 = (__bf16*)out  + (size_t)row * ldo + col0;
        __bf16* o2 = (__bf16*)out2 + (size_t)row * ldo + col0;
        #pragma unroll
        for (int n = 0; n < 4; ++n) {
          const float v = acc[m][n][r];
          o1[n * 16 + (l & 15)] = (__bf16)v;
          o2[n * 16 + (l & 15)] = (__bf16)((v - mu) * rsv * wlv[n] + blv[n]);
        }
      }
    }
  } else {
    #pragma unroll
    for (int m = 0; m < MR; ++m) {
      #pragma unroll
      for (int r = 0; r < 4; ++r) {
        const int row = row0 + wr * (BM / 2) + m * 16 + ((l >> 4) << 2) + r;
        float v[4];
        #pragma unroll
        for (int n = 0; n < 4; ++n) {
          v[n] = acc[m][n][r] + bs[n];
          if (ACT) v[n] = mishf(v[n]);
        }
        if (RES) {
          if constexpr (RESBF) {
            const __bf16* rp = (const __bf16*)res + (size_t)row * ldo + col0;
            #pragma unroll
            for (int n = 0; n < 4; ++n) v[n] += (float)rp[n * 16 + (l & 15)];
          } else {
            const float* rp = (const float*)res + (size_t)row * ldo + col0;
            #pragma unroll
            for (int n = 0; n < 4; ++n) v[n] += rp[n * 16 + (l & 15)];
          }
        }
        if (OUTBF) {
          __bf16* op = (__bf16*)out + (size_t)row * ldo + col0;
          #pragma unroll
          for (int n = 0; n < 4; ++n) op[n * 16 + (l & 15)] = (__bf16)v[n];
        } else {
          float* op = (float*)out + (size_t)row * ldo + col0;
          #pragma unroll
          for (int n = 0; n < 4; ++n) op[n * 16 + (l & 15)] = v[n];
        }
      }
    }
  }
}

// ---------------- flash attention over packed QKV [M][768] ----------------
// R9-proven version (75.5 us): 1D grid 256, XCD-chunked; 512 thr / 8 waves,
// 16 q-rows per wave. Measured floor of this structure: 6 neighboring
// variants (more/fewer q-rows, split-KV, e-split, swizzles) all regressed.
__global__ __launch_bounds__(512) void attn_fwd(
    const __bf16* __restrict__ QKV, __bf16* __restrict__ Om)
{
  __shared__ __bf16 Ks[2][32][256];   // K tile, XOR-swizzled rows
  __shared__ __bf16 Vs[2][256][32];   // V^T tile [n][k]
  __shared__ __bf16 Ps[8][16][32];    // per-wave P relayout buffer
  const int tid = threadIdx.x, l = tid & 63, w = tid >> 6;
  const int wgs = (blockIdx.x & 7) * 32 + (blockIdx.x >> 3);
  const int bh = wgs >> 3, qt = wgs & 7;
  const size_t rbase = (size_t)bh * 1024 * 768;   // bh row base in QKV
  const int qr0 = qt * 128 + w * 16;

  bf16x8 qf[8];
  {
    const __bf16* qp = QKV + rbase + (size_t)(qr0 + (l & 15)) * 768 + ((l >> 4) << 3);
    #pragma unroll
    for (int s = 0; s < 8; ++s) qf[s] = *(const bf16x8*)(qp + s * 32);
  }
  f32x4 acc[16] = {};
  float lacc[4] = {0.f, 0.f, 0.f, 0.f};

  const int kec = tid & 31, kr_ = tid >> 5;
  const int vp = tid & 15, vc = tid >> 4;
  const __bf16* gK = QKV + 256 + rbase + kec * 8;
  const __bf16* gV = QKV + 512 + rbase + vc * 8;

  uint4 rk0, rk1, rv0, rv1;
  auto ldKV = [&](int kt) {
    const __bf16* k0 = gK + (size_t)(kt * 32 + kr_) * 768;
    rk0 = *(const uint4*)k0;
    rk1 = *(const uint4*)(k0 + 16 * 768);
    const __bf16* v0 = gV + (size_t)(kt * 32 + vp * 2) * 768;
    rv0 = *(const uint4*)v0;
    rv1 = *(const uint4*)(v0 + 768);
  };
  auto wrKV = [&](int buf) {
    char* kb = (char*)&Ks[buf][0][0];
    const int a0 = (kr_ * 512 + kec * 16) ^ ((kr_ & 15) << 4);
    const int a1 = ((kr_ + 16) * 512 + kec * 16) ^ (((kr_ + 16) & 15) << 4);
    *(uint4*)(kb + a0) = rk0;
    *(uint4*)(kb + a1) = rk1;
    const ushort_t* s0 = (const ushort_t*)&rv0;
    const ushort_t* s1 = (const ushort_t*)&rv1;
    #pragma unroll
    for (int i = 0; i < 8; ++i) {
      unsigned pk = (unsigned)s0[i] | ((unsigned)s1[i] << 16);
      *(unsigned*)&Vs[buf][vc * 8 + i][vp * 2] = pk;
    }
  };

  ldKV(0); wrKV(0);
  __syncthreads();
  int cur = 0;
  for (int kt = 0;;) {
    if (kt + 1 < 32) ldKV(kt + 1);
    f32x4 S[2] = {};
    const char* kbase = (const char*)&Ks[cur][0][0];
    #pragma unroll
    for (int t = 0; t < 2; ++t) {
      const int kcol = t * 16 + (l & 15);
      const int swz = (kcol & 15) << 4;
      #pragma unroll
      for (int s = 0; s < 8; ++s) {
        uint4 kf = *(const uint4*)(kbase + ((kcol * 512 + s * 64 + ((l >> 4) << 4)) ^ swz));
        S[t] = __builtin_amdgcn_mfma_f32_16x16x32_bf16(qf[s], __builtin_bit_cast(bf16x8, kf), S[t], 0, 0, 0);
      }
    }
    #pragma unroll
    for (int t = 0; t < 2; ++t)
      #pragma unroll
      for (int r = 0; r < 4; ++r) {
        float p = __expf(S[t][r]);
        lacc[r] += p;
        Ps[w][((l >> 4) << 2) + r][t * 16 + (l & 15)] = (__bf16)p;
      }
    bf16x8 pf = *(const bf16x8*)&Ps[w][l & 15][(l >> 4) << 3];
    #pragma unroll
    for (int n = 0; n < 16; ++n) {
      uint4 vf = *(const uint4*)&Vs[cur][n * 16 + (l & 15)][(l >> 4) << 3];
      acc[n] = __builtin_amdgcn_mfma_f32_16x16x32_bf16(pf, __builtin_bit_cast(bf16x8, vf), acc[n], 0, 0, 0);
    }
    if (++kt == 32) break;
    wrKV(cur ^ 1);
    __syncthreads();
    cur ^= 1;
  }
  f32x4 inv;
  #pragma unroll
  for (int r = 0; r < 4; ++r) {
    float s = lacc[r];
    s += __shfl_xor(s, 1); s += __shfl_xor(s, 2);
    s += __shfl_xor(s, 4); s += __shfl_xor(s, 8);
    inv[r] = 1.f / (16.f * s);
  }
  __bf16* op = Om + (size_t)(bh * 1024 + qr0 + ((l >> 4) << 2)) * 256 + (l & 15);
  #pragma unroll
  for (int n = 0; n < 16; ++n)
    #pragma unroll
    for (int r = 0; r < 4; ++r)
      op[(size_t)r * 256 + n * 16] = (__bf16)(acc[n][r] * inv[r]);
}

// ---------------- host launch ----------------
extern "C" void kernel_launch(void* const* d_in, const int* in_sizes, int n_in,
                              void* d_out, int out_size, void* d_ws, size_t ws_size,
                              hipStream_t stream)
{
  const float* x    = (const float*)d_in[0];
  const float* ln1w = (const float*)d_in[1];
  const float* ln1b = (const float*)d_in[2];
  const float* Wq   = (const float*)d_in[3];
  const float* bq   = (const float*)d_in[4];
  const float* Wk   = (const float*)d_in[5];
  const float* bk   = (const float*)d_in[6];
  const float* Wv   = (const float*)d_in[7];
  const float* bv   = (const float*)d_in[8];
  const float* Wp   = (const float*)d_in[9];
  const float* bp   = (const float*)d_in[10];
  const float* ln2w = (const float*)d_in[11];
  const float* ln2b = (const float*)d_in[12];
  const float* W1   = (const float*)d_in[13];
  const float* b1   = (const float*)d_in[14];
  const float* W2   = (const float*)d_in[15];
  const float* b2   = (const float*)d_in[16];

  // ws layout (bytes):
  char* ws = (char*)d_ws;
  __bf16* wb   = (__bf16*)(ws);               // packed bf16 weights (1.5 MB)
  float*  bqkv = (float*)(ws + 1572864);      // packed qkv bias (3 KB)
  __bf16* y    = (__bf16*)(ws + 2097152);     // attn out (16 MB)
  __bf16* qkv  = (__bf16*)(ws + 18874368);    // packed QKV [M][768] (48 MB)
  __bf16* x1b  = (__bf16*)(ws + 18874368);    // x1 residual bf16 (16 MB, aliases qkv lo)
  __bf16* hb   = (__bf16*)(ws + 52428800);    // LN2 out (16 MB, aliases qkv hi)
  __bf16* h1   = (__bf16*)(ws + 69206016);    // MLP hidden (64 MB)
  __bf16* ao   = y;
  float*  outp = (float*)d_out;

  packw<<<385, 256, 0, stream>>>(Wq, Wk, Wv, Wp, W1, W2, bq, bk, bv, wb, bqkv);
  // QKV with fused LN1: A = LN(x) staged in-register
  bgemm<128, 3, 1, 0, 0, 1, 1, 0, 0><<<768, 512, 0, stream>>>(
      nullptr, x, wb, bqkv, nullptr, ln1w, ln1b, qkv, nullptr, 768);
  attn_fwd<<<256, 512, 0, stream>>>(qkv, ao);
  // proj with fused LN2: writes x1 (bf16) + hb = LN2(x1) (bf16); res = x fp32
  bgemm<64, 1, 1, 0, 1, 0, 0, 1, 0><<<512, 512, 0, stream>>>(
      ao, nullptr, wb + 196608, bp, x, ln2w, ln2b, x1b, hb, 256);
  // MLP1: mish, bf16 out [32768][1024]
  bgemm<128, 4, 1, 1, 0, 1, 0, 0, 0><<<1024, 512, 0, stream>>>(
      hb, nullptr, wb + 262144, b1, nullptr, nullptr, nullptr, h1, nullptr, 1024);
  // MLP2: K=1024, mish + x1 residual (bf16), fp32 out
  bgemm<64, 1, 4, 1, 1, 0, 0, 0, 1><<<512, 512, 0, stream>>>(
      h1, nullptr, wb + 524288, b2, x1b, nullptr, nullptr, outp, nullptr, 256);
}

// Round 23
// 193.160 us; speedup vs baseline: 1.1370x; 1.0090x over previous
//
#include <hip/hip_runtime.h>

typedef float  f32x4  __attribute__((ext_vector_type(4)));
typedef float  f4v    __attribute__((ext_vector_type(4)));
typedef __bf16 bf16x8 __attribute__((ext_vector_type(8)));
typedef __bf16 bf16x4 __attribute__((ext_vector_type(4)));
typedef unsigned short ushort_t;

#define AS1 __attribute__((address_space(1)))
#define AS3 __attribute__((address_space(3)))

static __device__ __forceinline__ void gload_lds16(const void* g, void* l) {
  __builtin_amdgcn_global_load_lds((const AS1 void*)g, (AS3 void*)l, 16, 0, 0);
}

// mish(x) = x * u/(u+2), u = t*(t+2), t = e^x; guard large x.
static __device__ __forceinline__ float mishf(float x) {
  float t = __expf(x);
  float u = t * (t + 2.f);
  float y = x * __fdividef(u, u + 2.f);
  return (x > 15.f) ? x : y;
}

// ---------------- weight pack: fp32 -> bf16 in MFMA-fragment order --------
// idx = ((((cb*KC + c)*8 + u)*2 + n)*64 + l)*8 holds
// W[cb*32 + n*16 + (l&15)][c*256 + u*32 + (l>>4)*8 .. +8].
// Block 384 additionally packs the qkv bias (768 floats).
__global__ __launch_bounds__(256) void packw(
    const float* __restrict__ Wq, const float* __restrict__ Wk,
    const float* __restrict__ Wv, const float* __restrict__ Wp,
    const float* __restrict__ W1, const float* __restrict__ W2,
    const float* __restrict__ bq, const float* __restrict__ bk,
    const float* __restrict__ bv, __bf16* __restrict__ out,
    float* __restrict__ bqkv)
{
  if (blockIdx.x == 384) {
    #pragma unroll
    for (int j = 0; j < 3; ++j) {
      const int i = j * 256 + threadIdx.x;
      bqkv[i] = (i < 256) ? bq[i] : (i < 512 ? bk[i - 256] : bv[i - 512]);
    }
    return;
  }
  const int t = blockIdx.x * 256 + threadIdx.x;   // 98304 threads
  const int e0 = t * 8;
  int rel, K; const float* src;
  if      (e0 < 196608) { rel = e0;          K = 256;  src = nullptr; }
  else if (e0 < 262144) { rel = e0 - 196608; K = 256;  src = Wp; }
  else if (e0 < 524288) { rel = e0 - 262144; K = 256;  src = W1; }
  else                  { rel = e0 - 524288; K = 1024; src = W2; }
  const int percb = (K >> 8) * 8192;
  const int cb = rel / percb;  const int r1 = rel % percb;
  const int c  = r1 / 8192;    const int r2 = r1 % 8192;
  const int u  = r2 / 1024;    const int r3 = r2 % 1024;
  const int n  = r3 / 512;     const int l  = (r3 % 512) >> 3;
  const int col = cb * 32 + n * 16 + (l & 15);
  const int k   = c * 256 + u * 32 + ((l >> 4) << 3);
  const float* sp;
  if (e0 < 196608) {
    const float* qkvsrc = (col < 256) ? Wq : (col < 512 ? Wk : Wv);
    sp = qkvsrc + (size_t)(col & 255) * 256 + k;
  } else {
    sp = src + (size_t)col * K + k;
  }
  const f4v a = *(const f4v*)(sp);
  const f4v b = *(const f4v*)(sp + 4);
  bf16x8 o;
  #pragma unroll
  for (int j = 0; j < 4; ++j) { o[j] = (__bf16)a[j]; o[4 + j] = (__bf16)b[j]; }
  *(bf16x8*)(out + e0) = o;
}

// ---------------- B-streamed GEMM, 128-wide double-buffered chunks --------
// out[M=32768][ldo](+nt*256) = act(A @ W^T + bias) (+res). NCH = K/128
// chunks; stage(c+1) issued BEFORE compute(c) into the idle buffer ->
// HBM staging latency hides under MFMA (previously 100% serial). One
// __syncthreads per chunk (its vmcnt(0)+barrier drains the prefetch).
// LDS 2x(BM*256B) keeps 2 blocks/CU. Block 512 thr / 8 waves (2x4).
// LNSTAGE: A = LayerNorm(Xf), both buffers pre-filled in-register.
// LNFUSE (BM=64): epilogue block-LN writes x1(bf16) + LN2(x1)(bf16).
template<int BM, int NT, int K, int ACT, int RES, int OUTBF,
         int LNSTAGE, int LNFUSE, int RESBF>
__global__ __launch_bounds__(512, 2) void bgemm(
    const __bf16* __restrict__ A, const float* __restrict__ Xf,
    const __bf16* __restrict__ Wg, const float* __restrict__ bias,
    const void* __restrict__ res, const float* __restrict__ lnw,
    const float* __restrict__ lnb, void* __restrict__ out,
    void* __restrict__ out2, int ldo)
{
  constexpr int NCH = K / 128;
  constexpr int KCP = K / 256;             // packed-W 256-chunk count
  constexpr int MR  = BM / 32;             // m-frags per wave (BM/2 rows)
  __shared__ __bf16 Ab[2][BM * 128];
  __shared__ float redS[64][4];
  __shared__ float redQ[64][4];
  const int tid = threadIdx.x, l = tid & 63, w = tid >> 6;
  const int wr = w >> 2, wc = w & 3;
  constexpr int nwg = (32768 / BM) * NT;
  const int wg = (blockIdx.x & 7) * (nwg / 8) + (blockIdx.x >> 3);
  const int mt = wg / NT, nt = wg % NT;
  const int row0 = mt * BM;
  const int col0 = nt * 256 + wc * 64;
  const int cb0 = nt * 8 + wc * 2;         // first of two 32-col blocks

  auto stageA = [&](int c, int b) {
    #pragma unroll
    for (int j = 0; j < BM / 32; ++j) {    // BM*16 units / 512 threads
      const int s = j * 512 + tid;
      const int r = s >> 4, q = s & 15;
      gload_lds16(A + (size_t)(row0 + r) * K + c * 128 + ((q ^ (r & 7)) << 3),
                  &Ab[b][s << 3]);
    }
  };

  auto ldBu = [&](bf16x8* d, int c, int u) {
    const int kc = c >> 1, uu = ((c & 1) << 2) + u;
    const __bf16* wp0 = Wg + ((size_t)cb0 * KCP + kc) * 8192 + (((uu << 1) * 64 + l) << 3);
    const __bf16* wp1 = wp0 + (size_t)KCP * 8192;
    d[0] = *(const bf16x8*)(wp0);
    d[1] = *(const bf16x8*)(wp0 + 512);
    d[2] = *(const bf16x8*)(wp1);
    d[3] = *(const bf16x8*)(wp1 + 512);
  };

  f32x4 acc[MR][4] = {};

  if constexpr (LNSTAGE) {
    // A = LayerNorm(Xf): fill BOTH chunk buffers in one pass
    const int q = tid & 31;
    const f4v ga0 = *(const f4v*)(lnw + q * 8);
    const f4v ga1 = *(const f4v*)(lnw + q * 8 + 4);
    const f4v bb0 = *(const f4v*)(lnb + q * 8);
    const f4v bb1 = *(const f4v*)(lnb + q * 8 + 4);
    #pragma unroll
    for (int j = 0; j < BM / 16; ++j) {
      const int s = j * 512 + tid, r = s >> 5;
      const float* xp = Xf + (size_t)(row0 + r) * 256 + q * 8;
      const f4v xa = *(const f4v*)xp;
      const f4v xb = *(const f4v*)(xp + 4);
      float s1 = xa[0] + xa[1] + xa[2] + xa[3] + xb[0] + xb[1] + xb[2] + xb[3];
      float s2 = xa[0]*xa[0] + xa[1]*xa[1] + xa[2]*xa[2] + xa[3]*xa[3]
               + xb[0]*xb[0] + xb[1]*xb[1] + xb[2]*xb[2] + xb[3]*xb[3];
      #pragma unroll
      for (int mk = 1; mk < 32; mk <<= 1) {
        s1 += __shfl_xor(s1, mk); s2 += __shfl_xor(s2, mk);
      }
      const float mu = s1 * (1.f / 256.f);
      const float rs = rsqrtf(s2 * (1.f / 256.f) - mu * mu + 1e-5f);
      bf16x8 o;
      #pragma unroll
      for (int i = 0; i < 4; ++i) {
        o[i]     = (__bf16)((xa[i] - mu) * rs * ga0[i] + bb0[i]);
        o[4 + i] = (__bf16)((xb[i] - mu) * rs * ga1[i] + bb1[i]);
      }
      *(bf16x8*)&Ab[q >> 4][((r << 4) | ((q & 15) ^ (r & 7))) << 3] = o;
    }
    __syncthreads();
  } else {
    stageA(0, 0);
    asm volatile("s_waitcnt vmcnt(0)" ::: "memory");
    __builtin_amdgcn_s_barrier();
  }

  for (int c = 0;;) {
    const int b = c & 1;
    if constexpr (!LNSTAGE) {
      if (c + 1 < NCH) stageA(c + 1, b ^ 1);  // prefetch into idle buffer
    }
    bf16x8 b0[4], b1[4];
    ldBu(b0, c, 0);
    #pragma unroll
    for (int u = 0; u < 4; ++u) {
      if (u + 1 < 4) ldBu((u & 1) ? b0 : b1, c, u + 1);
      const bf16x8* bu = (u & 1) ? b1 : b0;
      bf16x8 af[MR];
      #pragma unroll
      for (int m = 0; m < MR; ++m) {
        const int r = wr * (BM / 2) + m * 16 + (l & 15);
        const int q = ((u << 2) | (l >> 4)) ^ (r & 7);
        af[m] = *(const bf16x8*)&Ab[b][((r << 4) | q) << 3];
      }
      #pragma unroll
      for (int m = 0; m < MR; ++m)
        #pragma unroll
        for (int n = 0; n < 4; ++n)
          acc[m][n] = __builtin_amdgcn_mfma_f32_16x16x32_bf16(af[m], bu[n], acc[m][n], 0, 0, 0);
    }
    if (++c == NCH) break;
    __syncthreads();   // vmcnt(0)+barrier: prefetch landed, buffer retired
  }

  float bs[4];
  #pragma unroll
  for (int n = 0; n < 4; ++n) bs[n] = bias[col0 + n * 16 + (l & 15)];

  if constexpr (LNFUSE) {
    #pragma unroll
    for (int m = 0; m < MR; ++m) {
      #pragma unroll
      for (int r = 0; r < 4; ++r) {
        const int row = row0 + wr * (BM / 2) + m * 16 + ((l >> 4) << 2) + r;
        const float* rp = (const float*)res + (size_t)row * ldo + col0;
        float s1v = 0.f, s2v = 0.f;
        #pragma unroll
        for (int n = 0; n < 4; ++n) {
          float v = acc[m][n][r] + bs[n] + rp[n * 16 + (l & 15)];
          acc[m][n][r] = v;
          s1v += v; s2v += v * v;
        }
        #pragma unroll
        for (int mk = 1; mk < 16; mk <<= 1) {
          s1v += __shfl_xor(s1v, mk); s2v += __shfl_xor(s2v, mk);
        }
        if ((l & 15) == 0) { redS[row - row0][wc] = s1v; redQ[row - row0][wc] = s2v; }
      }
    }
    __syncthreads();
    float wlv[4], blv[4];
    #pragma unroll
    for (int n = 0; n < 4; ++n) {
      wlv[n] = lnw[col0 + n * 16 + (l & 15)];
      blv[n] = lnb[col0 + n * 16 + (l & 15)];
    }
    #pragma unroll
    for (int m = 0; m < MR; ++m) {
      #pragma unroll
      for (int r = 0; r < 4; ++r) {
        const int row = row0 + wr * (BM / 2) + m * 16 + ((l >> 4) << 2) + r;
        const int lrow = row - row0;
        const f4v ss = *(const f4v*)redS[lrow];
        const f4v qq = *(const f4v*)redQ[lrow];
        const float mu = (ss[0] + ss[1] + ss[2] + ss[3]) * (1.f / 256.f);
        const float var = (qq[0] + qq[1] + qq[2] + qq[3]) * (1.f / 256.f) - mu * mu;
        const float rsv = rsqrtf(var + 1e-5f);
        __bf16* o1 = (__bf16*)out  + (size_t)row * ldo + col0;
        __bf16* o2 = (__bf16*)out2 + (size_t)row * ldo + col0;
        #pragma unroll
        for (int n = 0; n < 4; ++n) {
          const float v = acc[m][n][r];
          o1[n * 16 + (l & 15)] = (__bf16)v;
          o2[n * 16 + (l & 15)] = (__bf16)((v - mu) * rsv * wlv[n] + blv[n]);
        }
      }
    }
  } else {
    #pragma unroll
    for (int m = 0; m < MR; ++m) {
      #pragma unroll
      for (int r = 0; r < 4; ++r) {
        const int row = row0 + wr * (BM / 2) + m * 16 + ((l >> 4) << 2) + r;
        float v[4];
        #pragma unroll
        for (int n = 0; n < 4; ++n) {
          v[n] = acc[m][n][r] + bs[n];
          if (ACT) v[n] = mishf(v[n]);
        }
        if (RES) {
          if constexpr (RESBF) {
            const __bf16* rp = (const __bf16*)res + (size_t)row * ldo + col0;
            #pragma unroll
            for (int n = 0; n < 4; ++n) v[n] += (float)rp[n * 16 + (l & 15)];
          } else {
            const float* rp = (const float*)res + (size_t)row * ldo + col0;
            #pragma unroll
            for (int n = 0; n < 4; ++n) v[n] += rp[n * 16 + (l & 15)];
          }
        }
        if (OUTBF) {
          __bf16* op = (__bf16*)out + (size_t)row * ldo + col0;
          #pragma unroll
          for (int n = 0; n < 4; ++n) op[n * 16 + (l & 15)] = (__bf16)v[n];
        } else {
          float* op = (float*)out + (size_t)row * ldo + col0;
          #pragma unroll
          for (int n = 0; n < 4; ++n) op[n * 16 + (l & 15)] = v[n];
        }
      }
    }
  }
}

// ---------------- flash attention over packed QKV [M][768] ----------------
// R9-proven version (75.5 us): 1D grid 256, XCD-chunked; 512 thr / 8 waves,
// 16 q-rows per wave. Measured floor of this structure (6 variants mapped).
__global__ __launch_bounds__(512) void attn_fwd(
    const __bf16* __restrict__ QKV, __bf16* __restrict__ Om)
{
  __shared__ __bf16 Ks[2][32][256];   // K tile, XOR-swizzled rows
  __shared__ __bf16 Vs[2][256][32];   // V^T tile [n][k]
  __shared__ __bf16 Ps[8][16][32];    // per-wave P relayout buffer
  const int tid = threadIdx.x, l = tid & 63, w = tid >> 6;
  const int wgs = (blockIdx.x & 7) * 32 + (blockIdx.x >> 3);
  const int bh = wgs >> 3, qt = wgs & 7;
  const size_t rbase = (size_t)bh * 1024 * 768;   // bh row base in QKV
  const int qr0 = qt * 128 + w * 16;

  bf16x8 qf[8];
  {
    const __bf16* qp = QKV + rbase + (size_t)(qr0 + (l & 15)) * 768 + ((l >> 4) << 3);
    #pragma unroll
    for (int s = 0; s < 8; ++s) qf[s] = *(const bf16x8*)(qp + s * 32);
  }
  f32x4 acc[16] = {};
  float lacc[4] = {0.f, 0.f, 0.f, 0.f};

  const int kec = tid & 31, kr_ = tid >> 5;
  const int vp = tid & 15, vc = tid >> 4;
  const __bf16* gK = QKV + 256 + rbase + kec * 8;
  const __bf16* gV = QKV + 512 + rbase + vc * 8;

  uint4 rk0, rk1, rv0, rv1;
  auto ldKV = [&](int kt) {
    const __bf16* k0 = gK + (size_t)(kt * 32 + kr_) * 768;
    rk0 = *(const uint4*)k0;
    rk1 = *(const uint4*)(k0 + 16 * 768);
    const __bf16* v0 = gV + (size_t)(kt * 32 + vp * 2) * 768;
    rv0 = *(const uint4*)v0;
    rv1 = *(const uint4*)(v0 + 768);
  };
  auto wrKV = [&](int buf) {
    char* kb = (char*)&Ks[buf][0][0];
    const int a0 = (kr_ * 512 + kec * 16) ^ ((kr_ & 15) << 4);
    const int a1 = ((kr_ + 16) * 512 + kec * 16) ^ (((kr_ + 16) & 15) << 4);
    *(uint4*)(kb + a0) = rk0;
    *(uint4*)(kb + a1) = rk1;
    const ushort_t* s0 = (const ushort_t*)&rv0;
    const ushort_t* s1 = (const ushort_t*)&rv1;
    #pragma unroll
    for (int i = 0; i < 8; ++i) {
      unsigned pk = (unsigned)s0[i] | ((unsigned)s1[i] << 16);
      *(unsigned*)&Vs[buf][vc * 8 + i][vp * 2] = pk;
    }
  };

  ldKV(0); wrKV(0);
  __syncthreads();
  int cur = 0;
  for (int kt = 0;;) {
    if (kt + 1 < 32) ldKV(kt + 1);
    f32x4 S[2] = {};
    const char* kbase = (const char*)&Ks[cur][0][0];
    #pragma unroll
    for (int t = 0; t < 2; ++t) {
      const int kcol = t * 16 + (l & 15);
      const int swz = (kcol & 15) << 4;
      #pragma unroll
      for (int s = 0; s < 8; ++s) {
        uint4 kf = *(const uint4*)(kbase + ((kcol * 512 + s * 64 + ((l >> 4) << 4)) ^ swz));
        S[t] = __builtin_amdgcn_mfma_f32_16x16x32_bf16(qf[s], __builtin_bit_cast(bf16x8, kf), S[t], 0, 0, 0);
      }
    }
    #pragma unroll
    for (int t = 0; t < 2; ++t)
      #pragma unroll
      for (int r = 0; r < 4; ++r) {
        float p = __expf(S[t][r]);
        lacc[r] += p;
        Ps[w][((l >> 4) << 2) + r][t * 16 + (l & 15)] = (__bf16)p;
      }
    bf16x8 pf = *(const bf16x8*)&Ps[w][l & 15][(l >> 4) << 3];
    #pragma unroll
    for (int n = 0; n < 16; ++n) {
      uint4 vf = *(const uint4*)&Vs[cur][n * 16 + (l & 15)][(l >> 4) << 3];
      acc[n] = __builtin_amdgcn_mfma_f32_16x16x32_bf16(pf, __builtin_bit_cast(bf16x8, vf), acc[n], 0, 0, 0);
    }
    if (++kt == 32) break;
    wrKV(cur ^ 1);
    __syncthreads();
    cur ^= 1;
  }
  f32x4 inv;
  #pragma unroll
  for (int r = 0; r < 4; ++r) {
    float s = lacc[r];
    s += __shfl_xor(s, 1); s += __shfl_xor(s, 2);
    s += __shfl_xor(s, 4); s += __shfl_xor(s, 8);
    inv[r] = 1.f / (16.f * s);
  }
  __bf16* op = Om + (size_t)(bh * 1024 + qr0 + ((l >> 4) << 2)) * 256 + (l & 15);
  #pragma unroll
  for (int n = 0; n < 16; ++n)
    #pragma unroll
    for (int r = 0; r < 4; ++r)
      op[(size_t)r * 256 + n * 16] = (__bf16)(acc[n][r] * inv[r]);
}

// ---------------- host launch ----------------
extern "C" void kernel_launch(void* const* d_in, const int* in_sizes, int n_in,
                              void* d_out, int out_size, void* d_ws, size_t ws_size,
                              hipStream_t stream)
{
  const float* x    = (const float*)d_in[0];
  const float* ln1w = (const float*)d_in[1];
  const float* ln1b = (const float*)d_in[2];
  const float* Wq   = (const float*)d_in[3];
  const float* bq   = (const float*)d_in[4];
  const float* Wk   = (const float*)d_in[5];
  const float* bk   = (const float*)d_in[6];
  const float* Wv   = (const float*)d_in[7];
  const float* bv   = (const float*)d_in[8];
  const float* Wp   = (const float*)d_in[9];
  const float* bp   = (const float*)d_in[10];
  const float* ln2w = (const float*)d_in[11];
  const float* ln2b = (const float*)d_in[12];
  const float* W1   = (const float*)d_in[13];
  const float* b1   = (const float*)d_in[14];
  const float* W2   = (const float*)d_in[15];
  const float* b2   = (const float*)d_in[16];

  // ws layout (bytes):
  char* ws = (char*)d_ws;
  __bf16* wb   = (__bf16*)(ws);               // packed bf16 weights (1.5 MB)
  float*  bqkv = (float*)(ws + 1572864);      // packed qkv bias (3 KB)
  __bf16* y    = (__bf16*)(ws + 2097152);     // attn out (16 MB)
  __bf16* qkv  = (__bf16*)(ws + 18874368);    // packed QKV [M][768] (48 MB)
  __bf16* x1b  = (__bf16*)(ws + 18874368);    // x1 residual bf16 (16 MB, aliases qkv lo)
  __bf16* hb   = (__bf16*)(ws + 52428800);    // LN2 out (16 MB, aliases qkv hi)
  __bf16* h1   = (__bf16*)(ws + 69206016);    // MLP hidden (64 MB)
  __bf16* ao   = y;
  float*  outp = (float*)d_out;

  packw<<<385, 256, 0, stream>>>(Wq, Wk, Wv, Wp, W1, W2, bq, bk, bv, wb, bqkv);
  // QKV with fused LN1: A = LN(x) staged in-register
  bgemm<128, 3, 256, 0, 0, 1, 1, 0, 0><<<768, 512, 0, stream>>>(
      nullptr, x, wb, bqkv, nullptr, ln1w, ln1b, qkv, nullptr, 768);
  attn_fwd<<<256, 512, 0, stream>>>(qkv, ao);
  // proj with fused LN2: writes x1 (bf16) + hb = LN2(x1) (bf16); res = x fp32
  bgemm<64, 1, 256, 0, 1, 0, 0, 1, 0><<<512, 512, 0, stream>>>(
      ao, nullptr, wb + 196608, bp, x, ln2w, ln2b, x1b, hb, 256);
  // MLP1: mish, bf16 out [32768][1024]
  bgemm<128, 4, 256, 1, 0, 1, 0, 0, 0><<<1024, 512, 0, stream>>>(
      hb, nullptr, wb + 262144, b1, nullptr, nullptr, nullptr, h1, nullptr, 1024);
  // MLP2: K=1024 (8 chunks, dbuf pipelined), mish + x1 residual (bf16), fp32 out
  bgemm<64, 1, 1024, 1, 1, 0, 0, 0, 1><<<512, 512, 0, stream>>>(
      h1, nullptr, wb + 524288, b2, x1b, nullptr, nullptr, outp, nullptr, 256);
}